// Round 1
// baseline (4742.585 us; speedup 1.0000x reference)
//
#include <hip/hip_runtime.h>
#include <hip/hip_bf16.h>
#include <math.h>

// Model: Conv1D(k=2, F=64, relu) -> LSTM(H=100, act=relu, rec_act=sigmoid,
// seq) -> LSTM(same, last) -> Dense(3) -> softmax.  B=128, T=2048, T'=2047.
// Design: one persistent block per batch element; gate-column weights in
// registers (thread g owns column g of [Wx;U]); h broadcast via LDS; cell
// state c in registers of threads 0..99. Two kernels chained on stream;
// h1 sequence staged in d_ws as bf16 [t][b][h] (52.4 MB).

#define BB 128
#define TT 2048
#define TP 2047      // conv 'valid' output length = LSTM steps
#define HH 100
#define G4 400       // 4*H, gate order i,f,g,o
#define FF 64

// ---------------- Kernel 1: conv + LSTM1 (persistent, 1 block = 1 batch) ----
__global__ __launch_bounds__(512, 2)
void lstm1_kernel(const float* __restrict__ s,       // [B,T]
                  const float* __restrict__ conv_w,  // [2,1,F]
                  const float* __restrict__ conv_b,  // [F]
                  const float* __restrict__ W,       // [F,4H]
                  const float* __restrict__ U,       // [H,4H]
                  const float* __restrict__ bias,    // [4H]
                  __hip_bfloat16* __restrict__ h1out)// [TP,B,H]
{
    const int b   = blockIdx.x;
    const int tid = threadIdx.x;

    __shared__ float s_buf[TT];                    // whole input row: 8 KB
    __shared__ __align__(16) float xh[FF + HH];    // [x(64) ; h(100)] = 164
    __shared__ float act[G4];

    for (int i = tid; i < TT; i += 512) s_buf[i] = s[(size_t)b * TT + i];
    if (tid < HH) xh[FF + tid] = 0.0f;

    // per-column weights in registers: wv[0..63]=W[:,g], wv[64..163]=U[:,g]
    float wv[FF + HH];
    float bg = 0.0f, cw0 = 0.0f, cw1 = 0.0f, cb = 0.0f;
    if (tid < G4) {
#pragma unroll
        for (int f = 0; f < FF; ++f) wv[f] = W[f * G4 + tid];
#pragma unroll
        for (int k = 0; k < HH; ++k) wv[FF + k] = U[k * G4 + tid];
        bg = bias[tid];
    }
    if (tid < FF) { cw0 = conv_w[tid]; cw1 = conv_w[FF + tid]; cb = conv_b[tid]; }

    float c = 0.0f;  // cell state, threads 0..99
    __syncthreads();

    for (int t = 0; t < TP; ++t) {
        // conv step: x[f] = relu(s_t*w0 + s_{t+1}*w1 + cb)
        if (tid < FF) {
            float xv = fmaf(s_buf[t], cw0, fmaf(s_buf[t + 1], cw1, cb));
            xh[tid] = fmaxf(xv, 0.0f);
        }
        __syncthreads();   // x(t) and h(t-1) visible

        if (tid < G4) {
            float z0 = bg, z1 = 0.f, z2 = 0.f, z3 = 0.f;
            const float4* xv4 = reinterpret_cast<const float4*>(xh);
#pragma unroll
            for (int q = 0; q < (FF + HH) / 4; ++q) {   // 41 ds_read_b128
                float4 v = xv4[q];
                z0 = fmaf(v.x, wv[4 * q + 0], z0);
                z1 = fmaf(v.y, wv[4 * q + 1], z1);
                z2 = fmaf(v.z, wv[4 * q + 2], z2);
                z3 = fmaf(v.w, wv[4 * q + 3], z3);
            }
            float z = (z0 + z1) + (z2 + z3);
            // cols: i[0,100) f[100,200) g[200,300) o[300,400)
            bool is_g = (tid >= 2 * HH) && (tid < 3 * HH);
            float a = is_g ? fmaxf(z, 0.0f) : 1.0f / (1.0f + __expf(-z));
            act[tid] = a;
        }
        __syncthreads();   // gates visible

        if (tid < HH) {
            float gi = act[tid], gf = act[HH + tid];
            float gg = act[2 * HH + tid], go = act[3 * HH + tid];
            c = fmaf(gf, c, gi * gg);
            float h = go * fmaxf(c, 0.0f);
            xh[FF + tid] = h;
            h1out[(size_t)(t * BB + b) * HH + tid] = __float2bfloat16(h);
        }
        // next iteration's top barrier orders the h/x writes vs z reads
    }
}

// ---------------- Kernel 2: LSTM2 + dense + softmax ------------------------
__global__ __launch_bounds__(512, 2)
void lstm2_kernel(const __hip_bfloat16* __restrict__ h1, // [TP,B,H]
                  const float* __restrict__ W,           // [H,4H]
                  const float* __restrict__ U,           // [H,4H]
                  const float* __restrict__ bias,        // [4H]
                  const float* __restrict__ dw,          // [H,3]
                  const float* __restrict__ db,          // [3]
                  float* __restrict__ out)               // [B,3]
{
    const int b   = blockIdx.x;
    const int tid = threadIdx.x;

    __shared__ __align__(16) float xh[2 * HH];   // [x(100)=h1_t ; h2(100)]
    __shared__ float act[G4];

    float wv[2 * HH];
    float bg = 0.0f;
    if (tid < G4) {
#pragma unroll
        for (int k = 0; k < HH; ++k) wv[k] = W[k * G4 + tid];
#pragma unroll
        for (int k = 0; k < HH; ++k) wv[HH + k] = U[k * G4 + tid];
        bg = bias[tid];
    }
    if (tid < HH) xh[HH + tid] = 0.0f;

    float c = 0.0f;
    // prefetch t=0 input
    float xnext = 0.0f;
    if (tid < HH) xnext = __bfloat162float(h1[(size_t)(0 * BB + b) * HH + tid]);
    __syncthreads();

    for (int t = 0; t < TP; ++t) {
        if (tid < HH) xh[tid] = xnext;
        __syncthreads();   // x(t) and h2(t-1) visible

        // prefetch next step's h1 row; latency hidden behind the FMA block
        if (tid < HH && (t + 1) < TP)
            xnext = __bfloat162float(h1[(size_t)((t + 1) * BB + b) * HH + tid]);

        if (tid < G4) {
            float z0 = bg, z1 = 0.f, z2 = 0.f, z3 = 0.f;
            const float4* xv4 = reinterpret_cast<const float4*>(xh);
#pragma unroll
            for (int q = 0; q < (2 * HH) / 4; ++q) {    // 50 ds_read_b128
                float4 v = xv4[q];
                z0 = fmaf(v.x, wv[4 * q + 0], z0);
                z1 = fmaf(v.y, wv[4 * q + 1], z1);
                z2 = fmaf(v.z, wv[4 * q + 2], z2);
                z3 = fmaf(v.w, wv[4 * q + 3], z3);
            }
            float z = (z0 + z1) + (z2 + z3);
            bool is_g = (tid >= 2 * HH) && (tid < 3 * HH);
            float a = is_g ? fmaxf(z, 0.0f) : 1.0f / (1.0f + __expf(-z));
            act[tid] = a;
        }
        __syncthreads();

        if (tid < HH) {
            float gi = act[tid], gf = act[HH + tid];
            float gg = act[2 * HH + tid], go = act[3 * HH + tid];
            c = fmaf(gf, c, gi * gg);
            xh[HH + tid] = go * fmaxf(c, 0.0f);
        }
    }
    __syncthreads();

    if (tid == 0) {
        float l[3];
#pragma unroll
        for (int a = 0; a < 3; ++a) {
            float acc = db[a];
            for (int j = 0; j < HH; ++j) acc = fmaf(xh[HH + j], dw[j * 3 + a], acc);
            l[a] = acc;
        }
        float m = fmaxf(l[0], fmaxf(l[1], l[2]));
        float e0 = __expf(l[0] - m), e1 = __expf(l[1] - m), e2 = __expf(l[2] - m);
        float inv = 1.0f / (e0 + e1 + e2);
        out[b * 3 + 0] = e0 * inv;
        out[b * 3 + 1] = e1 * inv;
        out[b * 3 + 2] = e2 * inv;
    }
}

// ---------------- launch ----------------------------------------------------
extern "C" void kernel_launch(void* const* d_in, const int* in_sizes, int n_in,
                              void* d_out, int out_size, void* d_ws, size_t ws_size,
                              hipStream_t stream) {
    const float* s      = (const float*)d_in[0];
    const float* conv_w = (const float*)d_in[1];
    const float* conv_b = (const float*)d_in[2];
    const float* w1     = (const float*)d_in[3];
    const float* u1     = (const float*)d_in[4];
    const float* b1     = (const float*)d_in[5];
    const float* w2     = (const float*)d_in[6];
    const float* u2     = (const float*)d_in[7];
    const float* b2     = (const float*)d_in[8];
    const float* dw     = (const float*)d_in[9];
    const float* db     = (const float*)d_in[10];

    __hip_bfloat16* h1 = (__hip_bfloat16*)d_ws;  // TP*B*H bf16 = 52.4 MB

    lstm1_kernel<<<BB, 512, 0, stream>>>(s, conv_w, conv_b, w1, u1, b1, h1);
    lstm2_kernel<<<BB, 512, 0, stream>>>(h1, w2, u2, b2, dw, db, (float*)d_out);
}

// Round 2
// 3061.134 us; speedup vs baseline: 1.5493x; 1.5493x over previous
//
#include <hip/hip_runtime.h>
#include <hip/hip_bf16.h>
#include <math.h>

// Conv1D(k=2,F=64,relu) -> LSTM1(H=100, relu cell, seq) -> LSTM2 (last) ->
// Dense(3) -> softmax.  B=128, T=2048, T'=2047.
//
// Round-2 design:
//  * ONE kernel, 256 blocks x 512 threads: blocks 0..127 = producer
//    (conv+LSTM1), blocks 128..255 = consumer (LSTM2+dense+softmax).
//    Producer b streams h1[t] (bf16, [t][b][h]) through d_ws; consumer b
//    follows with device-scope acquire on a per-batch progress counter.
//    Producers NEVER wait on consumers -> deadlock-free for any dispatch.
//  * Gate-column weights live in macro-named float4 REGISTERS (round 1 used
//    float arrays -> compiler left them in scratch: VGPR_Count=116, ~2400
//    cyc/step of L2 reload traffic).  Named float4s cannot be demoted.
//  * Progress words at d_ws[0..127]; 0xAA poison reads as negative int ->
//    consumer waits until producer publishes (monotonic t+1, every 8 steps).

#define BB 128
#define TT 2048
#define TP 2047
#define HH 100
#define G4 400
#define FF 64
#define CH 16          // consumer chunk (steps per progress check)

#define REP41(X) X(0) X(1) X(2) X(3) X(4) X(5) X(6) X(7) X(8) X(9) \
                 X(10) X(11) X(12) X(13) X(14) X(15) X(16) X(17) X(18) X(19) \
                 X(20) X(21) X(22) X(23) X(24) X(25) X(26) X(27) X(28) X(29) \
                 X(30) X(31) X(32) X(33) X(34) X(35) X(36) X(37) X(38) X(39) \
                 X(40)
#define REP50(X) REP41(X) X(41) X(42) X(43) X(44) X(45) X(46) X(47) X(48) X(49)

// combined [Wx; U] column element k of gate column g (nw = input width)
__device__ __forceinline__ float ldc(const float* __restrict__ W,
                                     const float* __restrict__ U,
                                     int nw, int k, int g) {
    return (k < nw) ? W[k * G4 + g] : U[(k - nw) * G4 + g];
}

#define DECLW(q) float4 w##q;
#define LOADP(q) w##q = make_float4(ldc(W,U,FF,4*(q)+0,g), ldc(W,U,FF,4*(q)+1,g), \
                                    ldc(W,U,FF,4*(q)+2,g), ldc(W,U,FF,4*(q)+3,g));
#define LOADC(q) w##q = make_float4(ldc(W,U,HH,4*(q)+0,g), ldc(W,U,HH,4*(q)+1,g), \
                                    ldc(W,U,HH,4*(q)+2,g), ldc(W,U,HH,4*(q)+3,g));
#define FMA4(q)  { float4 v = xv4[q]; z0 = fmaf(v.x, w##q.x, z0); \
                   z1 = fmaf(v.y, w##q.y, z1); z2 = fmaf(v.z, w##q.z, z2); \
                   z3 = fmaf(v.w, w##q.w, z3); }

__global__ __launch_bounds__(512, 2)
void fused_lstm_kernel(const float* __restrict__ s,       // [B,T]
                       const float* __restrict__ conv_w,  // [2,1,F]
                       const float* __restrict__ conv_b,  // [F]
                       const float* __restrict__ w1, const float* __restrict__ u1,
                       const float* __restrict__ b1,
                       const float* __restrict__ w2, const float* __restrict__ u2,
                       const float* __restrict__ b2,
                       const float* __restrict__ dw, const float* __restrict__ db,
                       __hip_bfloat16* __restrict__ h1,   // [TP,B,H] in d_ws
                       int* __restrict__ prog,            // [B] in d_ws
                       float* __restrict__ out)           // [B,3]
{
    const int tid = threadIdx.x;

    __shared__ float s_buf[TT];                 // producer only (8 KB)
    __shared__ __align__(16) float xh[208];     // [x ; h] (164 / 200 used)
    __shared__ float act[G4];

    if (blockIdx.x < BB) {
        // ================= PRODUCER: conv + LSTM1 =================
        const int b = blockIdx.x;
        const float* W = w1;
        const float* U = u1;
        const int g = (tid < G4) ? tid : 0;

        REP41(DECLW)
        REP41(LOADP)
        const float bg = b1[g];

        float cw0 = 0.f, cw1 = 0.f, cb = 0.f;
        if (tid < FF) { cw0 = conv_w[tid]; cw1 = conv_w[FF + tid]; cb = conv_b[tid]; }

        for (int i = tid; i < TT; i += 512) s_buf[i] = s[(size_t)b * TT + i];
        if (tid < HH) xh[FF + tid] = 0.0f;

        float c = 0.0f;
        __syncthreads();

        for (int t = 0; t < TP; ++t) {
            if (tid < FF)
                xh[tid] = fmaxf(fmaf(s_buf[t], cw0, fmaf(s_buf[t + 1], cw1, cb)), 0.0f);
            __syncthreads();                       // x(t), h(t-1) visible

            {
                float z0 = bg, z1 = 0.f, z2 = 0.f, z3 = 0.f;
                const float4* xv4 = reinterpret_cast<const float4*>(xh);
                REP41(FMA4)
                float z = (z0 + z1) + (z2 + z3);
                bool is_g = (tid >= 2 * HH) && (tid < 3 * HH);
                float a = is_g ? fmaxf(z, 0.0f) : 1.0f / (1.0f + __expf(-z));
                if (tid < G4) act[tid] = a;
            }
            __syncthreads();                       // gates visible

            if (tid < HH) {
                float gi = act[tid], gf = act[HH + tid];
                float gg = act[2 * HH + tid], go = act[3 * HH + tid];
                c = fmaf(gf, c, gi * gg);
                float h = go * fmaxf(c, 0.0f);
                xh[FF + tid] = h;
                h1[(size_t)(t * BB + b) * HH + tid] = __float2bfloat16(h);
            }
            // publish progress (every 8 steps + final)
            if ((((t + 1) & 7) == 0) || (t + 1) == TP) {
                if (tid < HH) __threadfence();     // drain h1 stores to agent scope
                __syncthreads();
                if (tid == 0)
                    __hip_atomic_store(&prog[b], t + 1, __ATOMIC_RELEASE,
                                       __HIP_MEMORY_SCOPE_AGENT);
            }
        }
    } else {
        // ================= CONSUMER: LSTM2 + dense + softmax =================
        const int b = blockIdx.x - BB;
        const float* W = w2;
        const float* U = u2;
        const int g = (tid < G4) ? tid : 0;

        REP50(DECLW)
        REP50(LOADC)
        const float bg = b2[g];

        if (tid < HH) xh[HH + tid] = 0.0f;

        float c = 0.0f;
        float xnext = 0.0f;
        int t = 0;
        const int NCH = (TP + CH - 1) / CH;

        for (int cc = 0; cc < NCH; ++cc) {
            const int tend = (CH * (cc + 1) < TP) ? CH * (cc + 1) : TP;
            const int need = (tend + 1 < TP) ? tend + 1 : TP;  // covers prefetch idx
            if (tid == 0) {
                while (__hip_atomic_load(&prog[b], __ATOMIC_ACQUIRE,
                                         __HIP_MEMORY_SCOPE_AGENT) < need)
                    __builtin_amdgcn_s_sleep(2);
            }
            __syncthreads();                       // all threads see released h1
            if (cc == 0 && tid < HH)
                xnext = __bfloat162float(h1[(size_t)b * HH + tid]);   // t=0 row

            for (; t < tend; ++t) {
                if (tid < HH) xh[tid] = xnext;
                __syncthreads();                   // x(t), h2(t-1) visible

                if (tid < HH && (t + 1) < TP)      // prefetch next row
                    xnext = __bfloat162float(h1[(size_t)((t + 1) * BB + b) * HH + tid]);

                {
                    float z0 = bg, z1 = 0.f, z2 = 0.f, z3 = 0.f;
                    const float4* xv4 = reinterpret_cast<const float4*>(xh);
                    REP50(FMA4)
                    float z = (z0 + z1) + (z2 + z3);
                    bool is_g = (tid >= 2 * HH) && (tid < 3 * HH);
                    float a = is_g ? fmaxf(z, 0.0f) : 1.0f / (1.0f + __expf(-z));
                    if (tid < G4) act[tid] = a;
                }
                __syncthreads();                   // gates visible

                if (tid < HH) {
                    float gi = act[tid], gf = act[HH + tid];
                    float gg = act[2 * HH + tid], go = act[3 * HH + tid];
                    c = fmaf(gf, c, gi * gg);
                    xh[HH + tid] = go * fmaxf(c, 0.0f);
                }
            }
        }
        __syncthreads();

        if (tid == 0) {
            float l[3];
#pragma unroll
            for (int a = 0; a < 3; ++a) {
                float acc = db[a];
                for (int j = 0; j < HH; ++j) acc = fmaf(xh[HH + j], dw[j * 3 + a], acc);
                l[a] = acc;
            }
            float m = fmaxf(l[0], fmaxf(l[1], l[2]));
            float e0 = __expf(l[0] - m), e1 = __expf(l[1] - m), e2 = __expf(l[2] - m);
            float inv = 1.0f / (e0 + e1 + e2);
            out[b * 3 + 0] = e0 * inv;
            out[b * 3 + 1] = e1 * inv;
            out[b * 3 + 2] = e2 * inv;
        }
    }
}

// ---------------- launch ----------------------------------------------------
extern "C" void kernel_launch(void* const* d_in, const int* in_sizes, int n_in,
                              void* d_out, int out_size, void* d_ws, size_t ws_size,
                              hipStream_t stream) {
    const float* s      = (const float*)d_in[0];
    const float* conv_w = (const float*)d_in[1];
    const float* conv_b = (const float*)d_in[2];
    const float* w1     = (const float*)d_in[3];
    const float* u1     = (const float*)d_in[4];
    const float* b1     = (const float*)d_in[5];
    const float* w2     = (const float*)d_in[6];
    const float* u2     = (const float*)d_in[7];
    const float* b2     = (const float*)d_in[8];
    const float* dw     = (const float*)d_in[9];
    const float* db     = (const float*)d_in[10];

    int* prog = (int*)d_ws;                                   // [128] flags (poison<0)
    __hip_bfloat16* h1 = (__hip_bfloat16*)((char*)d_ws + 512); // [TP,B,H] bf16

    fused_lstm_kernel<<<2 * BB, 512, 0, stream>>>(
        s, conv_w, conv_b, w1, u1, b1, w2, u2, b2, dw, db, h1, prog, (float*)d_out);
}

// Round 3
// 2575.730 us; speedup vs baseline: 1.8413x; 1.1885x over previous
//
#include <hip/hip_runtime.h>
#include <hip/hip_bf16.h>
#include <math.h>

// Conv1D(k=2,F=64,relu) -> LSTM1(H=100, relu cell, seq) -> LSTM2 (last) ->
// Dense(3) -> softmax.  B=128, T=2048, T'=2047.
//
// Round-3 design (changes vs round 2):
//  * Gate matvec via v_dot2_f32_f16 (__builtin_amdgcn_fdot2): weights packed
//    as f16 pairs in NAMED half2 registers -> 100 VGPRs/thread (consumer),
//    84 (producer).  Round 2's 200 fp32 regs/thread overflowed the
//    (512,2) cap and the allocator hid them in AGPRs: VGPR_Count=116 and
//    ~800 cyc/step/SIMD of v_accvgpr_read traffic.  Halving footprint AND
//    instruction count removes both.
//  * x / h / staged h1 are f16 (10-bit mantissa; replaces round-2 bf16 h1).
//  * Same producer/consumer split: blocks 0..127 conv+LSTM1, 128..255
//    LSTM2+dense+softmax, agent-scope progress handshake through d_ws.

typedef _Float16 h2 __attribute__((ext_vector_type(2)));

#define BB 128
#define TT 2048
#define TP 2047
#define HH 100
#define G4 400
#define FF 64
#define CH 16          // consumer chunk (steps per progress check)

// ---- list macros -----------------------------------------------------------
#define R84(X) X(0) X(1) X(2) X(3) X(4) X(5) X(6) X(7) X(8) X(9) \
  X(10) X(11) X(12) X(13) X(14) X(15) X(16) X(17) X(18) X(19) \
  X(20) X(21) X(22) X(23) X(24) X(25) X(26) X(27) X(28) X(29) \
  X(30) X(31) X(32) X(33) X(34) X(35) X(36) X(37) X(38) X(39) \
  X(40) X(41) X(42) X(43) X(44) X(45) X(46) X(47) X(48) X(49) \
  X(50) X(51) X(52) X(53) X(54) X(55) X(56) X(57) X(58) X(59) \
  X(60) X(61) X(62) X(63) X(64) X(65) X(66) X(67) X(68) X(69) \
  X(70) X(71) X(72) X(73) X(74) X(75) X(76) X(77) X(78) X(79) \
  X(80) X(81) X(82) X(83)
#define R100(X) R84(X) X(84) X(85) X(86) X(87) X(88) X(89) X(90) X(91) \
  X(92) X(93) X(94) X(95) X(96) X(97) X(98) X(99)

#define DECLW(q) h2 w##q;

// producer column element k (combined [conv-x W(64); U(100); pad(4)])
__device__ __forceinline__ _Float16 colP(const float* __restrict__ W,
                                         const float* __restrict__ U,
                                         int g, int k) {
    float v = (k < FF) ? W[k * G4 + g]
            : (k < FF + HH) ? U[(k - FF) * G4 + g] : 0.0f;
    return (_Float16)v;
}
// consumer column element k (combined [W(100); U(100)])
__device__ __forceinline__ _Float16 colC(const float* __restrict__ W,
                                         const float* __restrict__ U,
                                         int g, int k) {
    float v = (k < HH) ? W[k * G4 + g] : U[(k - HH) * G4 + g];
    return (_Float16)v;
}

#define LDP(q) w##q = h2{colP(W, U, g, 2*(q)), colP(W, U, g, 2*(q)+1)};
#define LDC(q) w##q = h2{colC(W, U, g, 2*(q)), colC(W, U, g, 2*(q)+1)};

// one float4 LDS read = 8 halves = 4 dot2s into 4 independent chains
#define D4(r, a, b, c, d) { float4 v = xv4[r]; \
  z0 = __builtin_amdgcn_fdot2(w##a, __builtin_bit_cast(h2, v.x), z0, false); \
  z1 = __builtin_amdgcn_fdot2(w##b, __builtin_bit_cast(h2, v.y), z1, false); \
  z2 = __builtin_amdgcn_fdot2(w##c, __builtin_bit_cast(h2, v.z), z2, false); \
  z3 = __builtin_amdgcn_fdot2(w##d, __builtin_bit_cast(h2, v.w), z3, false); }

__global__ __launch_bounds__(512, 2)
void fused_lstm_kernel(const float* __restrict__ s,       // [B,T]
                       const float* __restrict__ conv_w,  // [2,1,F]
                       const float* __restrict__ conv_b,  // [F]
                       const float* __restrict__ w1, const float* __restrict__ u1,
                       const float* __restrict__ b1,
                       const float* __restrict__ w2, const float* __restrict__ u2,
                       const float* __restrict__ b2,
                       const float* __restrict__ dw, const float* __restrict__ db,
                       _Float16* __restrict__ h1,         // [TP,B,H] in d_ws
                       int* __restrict__ prog,            // [B] in d_ws
                       float* __restrict__ out)           // [B,3]
{
    const int tid = threadIdx.x;

    __shared__ float s_buf[TT];                         // producer only, 8 KB
    __shared__ __align__(16) _Float16 xh[224];          // f16 [x ; h] (+pad)
    __shared__ float act[G4];

    if (blockIdx.x < BB) {
        // ================= PRODUCER: conv + LSTM1 =================
        const int b = blockIdx.x;
        const float* W = w1;
        const float* U = u1;
        const int g = (tid < G4) ? tid : 0;

        R84(DECLW)
        R84(LDP)
        const float bg = b1[g];

        float cw0 = 0.f, cw1 = 0.f, cb = 0.f;
        if (tid < FF) { cw0 = conv_w[tid]; cw1 = conv_w[FF + tid]; cb = conv_b[tid]; }

        for (int i = tid; i < TT; i += 512) s_buf[i] = s[(size_t)b * TT + i];
        if (tid < HH + 8) xh[FF + tid] = (_Float16)0.0f;  // h=0 and zero the pad

        float c = 0.0f;
        __syncthreads();

        for (int t = 0; t < TP; ++t) {
            if (tid < FF)
                xh[tid] = (_Float16)fmaxf(
                    fmaf(s_buf[t], cw0, fmaf(s_buf[t + 1], cw1, cb)), 0.0f);
            __syncthreads();                     // x(t), h(t-1) visible

            {
                float z0 = bg, z1 = 0.f, z2 = 0.f, z3 = 0.f;
                const float4* xv4 = reinterpret_cast<const float4*>(xh);
                D4(0,0,1,2,3)    D4(1,4,5,6,7)    D4(2,8,9,10,11)
                D4(3,12,13,14,15) D4(4,16,17,18,19) D4(5,20,21,22,23)
                D4(6,24,25,26,27) D4(7,28,29,30,31) D4(8,32,33,34,35)
                D4(9,36,37,38,39) D4(10,40,41,42,43) D4(11,44,45,46,47)
                D4(12,48,49,50,51) D4(13,52,53,54,55) D4(14,56,57,58,59)
                D4(15,60,61,62,63) D4(16,64,65,66,67) D4(17,68,69,70,71)
                D4(18,72,73,74,75) D4(19,76,77,78,79) D4(20,80,81,82,83)
                float z = (z0 + z1) + (z2 + z3);
                bool is_g = (tid >= 2 * HH) && (tid < 3 * HH);
                float a = is_g ? fmaxf(z, 0.0f) : 1.0f / (1.0f + __expf(-z));
                if (tid < G4) act[tid] = a;
            }
            __syncthreads();                     // gates visible

            if (tid < HH) {
                float gi = act[tid], gf = act[HH + tid];
                float gg = act[2 * HH + tid], go = act[3 * HH + tid];
                c = fmaf(gf, c, gi * gg);
                float h = go * fmaxf(c, 0.0f);
                _Float16 hq = (_Float16)h;
                xh[FF + tid] = hq;
                h1[(size_t)(t * BB + b) * HH + tid] = hq;
            }
            if ((((t + 1) & 7) == 0) || (t + 1) == TP) {   // publish progress
                if (tid < HH) __threadfence();
                __syncthreads();
                if (tid == 0)
                    __hip_atomic_store(&prog[b], t + 1, __ATOMIC_RELEASE,
                                       __HIP_MEMORY_SCOPE_AGENT);
            }
        }
    } else {
        // ================= CONSUMER: LSTM2 + dense + softmax =================
        const int b = blockIdx.x - BB;
        const float* W = w2;
        const float* U = u2;
        const int g = (tid < G4) ? tid : 0;

        R100(DECLW)
        R100(LDC)
        const float bg = b2[g];

        if (tid < HH) xh[HH + tid] = (_Float16)0.0f;    // h2(0) = 0

        float c = 0.0f;
        _Float16 xnext = (_Float16)0.0f;
        int t = 0;
        const int NCH = (TP + CH - 1) / CH;

        for (int cc = 0; cc < NCH; ++cc) {
            const int tend = (CH * (cc + 1) < TP) ? CH * (cc + 1) : TP;
            const int need = (tend + 1 < TP) ? tend + 1 : TP;
            if (tid == 0) {
                while (__hip_atomic_load(&prog[b], __ATOMIC_ACQUIRE,
                                         __HIP_MEMORY_SCOPE_AGENT) < need)
                    __builtin_amdgcn_s_sleep(2);
            }
            __syncthreads();                     // released h1 rows visible
            if (cc == 0 && tid < HH)
                xnext = h1[(size_t)b * HH + tid];            // t=0 row

            for (; t < tend; ++t) {
                if (tid < HH) xh[tid] = xnext;
                __syncthreads();                 // x(t), h2(t-1) visible

                if (tid < HH && (t + 1) < TP)    // prefetch next row
                    xnext = h1[(size_t)((t + 1) * BB + b) * HH + tid];

                {
                    float z0 = bg, z1 = 0.f, z2 = 0.f, z3 = 0.f;
                    const float4* xv4 = reinterpret_cast<const float4*>(xh);
                    D4(0,0,1,2,3)    D4(1,4,5,6,7)    D4(2,8,9,10,11)
                    D4(3,12,13,14,15) D4(4,16,17,18,19) D4(5,20,21,22,23)
                    D4(6,24,25,26,27) D4(7,28,29,30,31) D4(8,32,33,34,35)
                    D4(9,36,37,38,39) D4(10,40,41,42,43) D4(11,44,45,46,47)
                    D4(12,48,49,50,51) D4(13,52,53,54,55) D4(14,56,57,58,59)
                    D4(15,60,61,62,63) D4(16,64,65,66,67) D4(17,68,69,70,71)
                    D4(18,72,73,74,75) D4(19,76,77,78,79) D4(20,80,81,82,83)
                    D4(21,84,85,86,87) D4(22,88,89,90,91) D4(23,92,93,94,95)
                    D4(24,96,97,98,99)
                    float z = (z0 + z1) + (z2 + z3);
                    bool is_g = (tid >= 2 * HH) && (tid < 3 * HH);
                    float a = is_g ? fmaxf(z, 0.0f) : 1.0f / (1.0f + __expf(-z));
                    if (tid < G4) act[tid] = a;
                }
                __syncthreads();                 // gates visible

                if (tid < HH) {
                    float gi = act[tid], gf = act[HH + tid];
                    float gg = act[2 * HH + tid], go = act[3 * HH + tid];
                    c = fmaf(gf, c, gi * gg);
                    xh[HH + tid] = (_Float16)(go * fmaxf(c, 0.0f));
                }
            }
        }
        __syncthreads();

        if (tid == 0) {
            float l[3];
#pragma unroll
            for (int a = 0; a < 3; ++a) {
                float acc = db[a];
                for (int j = 0; j < HH; ++j)
                    acc = fmaf((float)xh[HH + j], dw[j * 3 + a], acc);
                l[a] = acc;
            }
            float m = fmaxf(l[0], fmaxf(l[1], l[2]));
            float e0 = __expf(l[0] - m), e1 = __expf(l[1] - m), e2 = __expf(l[2] - m);
            float inv = 1.0f / (e0 + e1 + e2);
            out[b * 3 + 0] = e0 * inv;
            out[b * 3 + 1] = e1 * inv;
            out[b * 3 + 2] = e2 * inv;
        }
    }
}

// ---------------- launch ----------------------------------------------------
extern "C" void kernel_launch(void* const* d_in, const int* in_sizes, int n_in,
                              void* d_out, int out_size, void* d_ws, size_t ws_size,
                              hipStream_t stream) {
    const float* s      = (const float*)d_in[0];
    const float* conv_w = (const float*)d_in[1];
    const float* conv_b = (const float*)d_in[2];
    const float* w1     = (const float*)d_in[3];
    const float* u1     = (const float*)d_in[4];
    const float* b1     = (const float*)d_in[5];
    const float* w2     = (const float*)d_in[6];
    const float* u2     = (const float*)d_in[7];
    const float* b2     = (const float*)d_in[8];
    const float* dw     = (const float*)d_in[9];
    const float* db     = (const float*)d_in[10];

    int* prog    = (int*)d_ws;                               // [128] (poison<0)
    _Float16* h1 = (_Float16*)((char*)d_ws + 512);           // [TP,B,H] f16

    fused_lstm_kernel<<<2 * BB, 512, 0, stream>>>(
        s, conv_w, conv_b, w1, u1, b1, w2, u2, b2, dw, db, h1, prog, (float*)d_out);
}